// Round 3
// baseline (1925.726 us; speedup 1.0000x reference)
//
#include <hip/hip_runtime.h>

#define NU 100000
#define NI 100000
#define NT 200000
#define D 64
#define NLAYERS 3
#define NNZ_TOTAL 3200000
#define ALPHA 0.2f

// ---------------- init: E = concat(user_table[uidx], item_table[iidx]), float4 ----------------
__global__ __launch_bounds__(256) void init_emb_kernel(
    const float* __restrict__ ut, const float* __restrict__ it,
    const int* __restrict__ uidx, const int* __restrict__ iidx,
    float* __restrict__ E)
{
    int i = blockIdx.x * 256 + threadIdx.x;          // float4 index; NT*16 = 3.2M
    if (i >= NT * 16) return;
    int n = i >> 4;
    int q = i & 15;
    const float4* src;
    if (n < NU) src = (const float4*)(ut + uidx[n] * D);
    else        src = (const float4*)(it + iidx[n - NU] * D);
    ((float4*)(E + n * D))[q] = src[q];
}

// ---------------- CSR build ----------------
__global__ __launch_bounds__(256) void hist_kernel(const int* __restrict__ rows,
                                                   int* __restrict__ counts)
{
    int i = blockIdx.x * 256 + threadIdx.x;
    if (i < NNZ_TOTAL) atomicAdd(&counts[rows[i]], 1);
}

__global__ __launch_bounds__(256) void scan_block_tot(const int* __restrict__ counts,
                                                      int* __restrict__ btot)
{
    __shared__ int s[256];
    int b = blockIdx.x, t = threadIdx.x;
    int base = b * 1024 + t * 4;
    int sum = 0;
#pragma unroll
    for (int j = 0; j < 4; ++j) { int idx = base + j; if (idx < NT) sum += counts[idx]; }
    s[t] = sum; __syncthreads();
    for (int off = 128; off > 0; off >>= 1) {
        if (t < off) s[t] += s[t + off];
        __syncthreads();
    }
    if (t == 0) btot[b] = s[0];
}

__global__ __launch_bounds__(256) void scan_btot(const int* __restrict__ btot,
                                                 int* __restrict__ boff,
                                                 int* __restrict__ row_ptr, int nb)
{
    __shared__ int s[256];
    int t = threadIdx.x;
    int v = (t < nb) ? btot[t] : 0;
    s[t] = v; __syncthreads();
    for (int off = 1; off < 256; off <<= 1) {
        int x = (t >= off) ? s[t - off] : 0;
        __syncthreads();
        s[t] += x;
        __syncthreads();
    }
    boff[t] = s[t] - v;                 // exclusive
    if (t == 255) row_ptr[NT] = s[255];
}

__global__ __launch_bounds__(256) void scan_final(const int* __restrict__ counts,
                                                  const int* __restrict__ boff,
                                                  int* __restrict__ row_ptr,
                                                  int* __restrict__ cursor)
{
    __shared__ int s[256];
    int b = blockIdx.x, t = threadIdx.x;
    int base = b * 1024 + t * 4;
    int c[4];
#pragma unroll
    for (int j = 0; j < 4; ++j) { int idx = base + j; c[j] = (idx < NT) ? counts[idx] : 0; }
    int tt = c[0] + c[1] + c[2] + c[3];
    s[t] = tt; __syncthreads();
    for (int off = 1; off < 256; off <<= 1) {
        int x = (t >= off) ? s[t - off] : 0;
        __syncthreads();
        s[t] += x;
        __syncthreads();
    }
    int ex = boff[b] + s[t] - tt;
#pragma unroll
    for (int j = 0; j < 4; ++j) {
        int idx = base + j;
        if (idx < NT) { row_ptr[idx] = ex; cursor[idx] = ex; }
        ex += c[j];
    }
}

// scatter: one interleaved 8B write per nnz (col, val) — halves random-line traffic
__global__ __launch_bounds__(256) void scatter_kernel(
    const int* __restrict__ rows, const int* __restrict__ cols,
    const float* __restrict__ vals, int* __restrict__ cursor,
    int2* __restrict__ csr)
{
    int i = blockIdx.x * 256 + threadIdx.x;
    if (i >= NNZ_TOTAL) return;
    int r = rows[i];
    int pos = atomicAdd(&cursor[r], 1);
    csr[pos] = make_int2(cols[i], __float_as_int(vals[i]));
}

// ---------------- fused layer: Enew = leakyrelu( R @ W1 + (R .* Eold) @ W2 ) ----------------
// R[r] = sum_j val_j * Eold[col_j]  computed inline (wave per row, lane = dim).
// Persistent waves; each wave holds both 64x64 weight matrices (column = lane) in VGPRs.
__global__ __launch_bounds__(256) void layer_kernel(
    const float* __restrict__ Eold, float* __restrict__ Enew,
    const int* __restrict__ row_ptr, const int2* __restrict__ csr,
    const float* __restrict__ W1, const float* __restrict__ W2)
{
    __shared__ float2 sAM[4][64];
    int t = threadIdx.x;
    int lane = t & 63;
    int wl = t >> 6;
    float w1r[64], w2r[64];
#pragma unroll
    for (int k = 0; k < 64; ++k) {
        w1r[k] = W1[k * 64 + lane];
        w2r[k] = W2[k * 64 + lane];
    }
    int gw = blockIdx.x * 4 + wl;
    int stride = gridDim.x * 4;
    for (int r = gw; r < NT; r += stride) {
        int beg = row_ptr[r], end = row_ptr[r + 1];
        float acc = 0.f;
        int j = beg;
        for (; j + 4 <= end; j += 4) {
            int2 p0 = csr[j], p1 = csr[j + 1], p2 = csr[j + 2], p3 = csr[j + 3];
            float e0 = Eold[p0.x * D + lane], e1 = Eold[p1.x * D + lane];
            float e2 = Eold[p2.x * D + lane], e3 = Eold[p3.x * D + lane];
            acc += __int_as_float(p0.y) * e0;
            acc += __int_as_float(p1.y) * e1;
            acc += __int_as_float(p2.y) * e2;
            acc += __int_as_float(p3.y) * e3;
        }
        for (; j < end; ++j) {
            int2 p = csr[j];
            acc += __int_as_float(p.y) * Eold[p.x * D + lane];
        }
        float e = Eold[r * D + lane];
        sAM[wl][lane] = make_float2(acc, acc * e);   // wave-private slice; lockstep, no barrier
        float o = 0.f;
#pragma unroll
        for (int k = 0; k < 64; ++k) {
            float2 am = sAM[wl][k];                  // broadcast read
            o += am.x * w1r[k] + am.y * w2r[k];
        }
        o = o > 0.f ? o : ALPHA * o;
        Enew[r * D + lane] = o;
    }
}

// ---------------- per-stage dot: out[n] (+)= dot(E[n], E[NU+n]) ----------------
__global__ __launch_bounds__(256) void dot_kernel(const float* __restrict__ E,
                                                  float* __restrict__ out, int first)
{
    int w = (blockIdx.x * 256 + threadIdx.x) >> 6;   // user index
    int lane = threadIdx.x & 63;
    if (w >= NU) return;
    float p = E[w * D + lane] * E[(NU + w) * D + lane];
#pragma unroll
    for (int off = 32; off > 0; off >>= 1) p += __shfl_xor(p, off);
    if (lane == 0) {
        if (first) out[w] = p;
        else       out[w] += p;
    }
}

extern "C" void kernel_launch(void* const* d_in, const int* in_sizes, int n_in,
                              void* d_out, int out_size, void* d_ws, size_t ws_size,
                              hipStream_t stream)
{
    const float* ut   = (const float*)d_in[0];
    const float* it   = (const float*)d_in[1];
    const float* W1   = (const float*)d_in[2];
    const float* W2   = (const float*)d_in[3];
    const float* vals = (const float*)d_in[4];
    const int*   rows = (const int*)d_in[5];
    const int*   cols = (const int*)d_in[6];
    const int*   uidx = (const int*)d_in[7];
    const int*   iidx = (const int*)d_in[8];
    float* out = (float*)d_out;

    char* ws = (char*)d_ws;
    float* Ea      = (float*)(ws + 0);           // 51,200,000 B
    float* Eb      = (float*)(ws + 51200000);    // 51,200,000 B
    int*   counts  = (int*)  (ws + 102400000);   // 800,000 B
    int*   cursor  = (int*)  (ws + 103200000);   // 800,000 B
    int*   row_ptr = (int*)  (ws + 104000000);   // 800,004 B (padded)
    int*   btot    = (int*)  (ws + 104800256);   // 1 KB
    int*   boff    = (int*)  (ws + 104801280);   // 1 KB
    int2*  csr     = (int2*) (ws + 104802304);   // 25,600,000 B -> end 130,402,304

    hipMemsetAsync(counts, 0, NT * 4, stream);

    init_emb_kernel<<<(NT * 16 + 255) / 256, 256, 0, stream>>>(ut, it, uidx, iidx, Ea);

    hist_kernel<<<(NNZ_TOTAL + 255) / 256, 256, 0, stream>>>(rows, counts);
    const int NB = (NT + 1023) / 1024;           // 196
    scan_block_tot<<<NB, 256, 0, stream>>>(counts, btot);
    scan_btot<<<1, 256, 0, stream>>>(btot, boff, row_ptr, NB);
    scan_final<<<NB, 256, 0, stream>>>(counts, boff, row_ptr, cursor);
    scatter_kernel<<<(NNZ_TOTAL + 255) / 256, 256, 0, stream>>>(rows, cols, vals, cursor, csr);

    dot_kernel<<<NU / 4, 256, 0, stream>>>(Ea, out, 1);   // stage 0

    float* Ecur = Ea;
    float* Enxt = Eb;
    for (int l = 0; l < NLAYERS; ++l) {
        layer_kernel<<<512, 256, 0, stream>>>(Ecur, Enxt, row_ptr, csr,
                                              W1 + l * 4096, W2 + l * 4096);
        dot_kernel<<<NU / 4, 256, 0, stream>>>(Enxt, out, 0);
        float* tmp = Ecur; Ecur = Enxt; Enxt = tmp;
    }
}

// Round 5
// 1081.916 us; speedup vs baseline: 1.7799x; 1.7799x over previous
//
#include <hip/hip_runtime.h>

#define NU 100000
#define NI 100000
#define NT 200000
#define D 64
#define NLAYERS 3
#define NNZ_TOTAL 3200000
#define ALPHA 0.2f

// ---------------- fused init + stage-0 dot ----------------
// wave per user index w: loads user row w and item row w (NI==NU), writes both
// into E, and emits out[w] = dot(u0, i0).
__global__ __launch_bounds__(256) void init_dot_kernel(
    const float* __restrict__ ut, const float* __restrict__ it,
    const int* __restrict__ uidx, const int* __restrict__ iidx,
    float* __restrict__ E, float* __restrict__ out)
{
    int w = (blockIdx.x * 256 + threadIdx.x) >> 6;   // user index
    int lane = threadIdx.x & 63;
    if (w >= NU) return;
    float eu = ut[uidx[w] * D + lane];
    float ei = it[iidx[w] * D + lane];
    E[w * D + lane] = eu;
    E[(NU + w) * D + lane] = ei;
    float p = eu * ei;
#pragma unroll
    for (int off = 32; off > 0; off >>= 1) p += __shfl_xor(p, off);
    if (lane == 0) out[w] = p;
}

// ---------------- CSR build ----------------
__global__ __launch_bounds__(256) void hist_kernel(const int* __restrict__ rows,
                                                   int* __restrict__ counts)
{
    int i = blockIdx.x * 256 + threadIdx.x;
    if (i < NNZ_TOTAL) atomicAdd(&counts[rows[i]], 1);
}

__global__ __launch_bounds__(256) void scan_block_tot(const int* __restrict__ counts,
                                                      int* __restrict__ btot)
{
    __shared__ int s[256];
    int b = blockIdx.x, t = threadIdx.x;
    int base = b * 1024 + t * 4;
    int sum = 0;
#pragma unroll
    for (int j = 0; j < 4; ++j) { int idx = base + j; if (idx < NT) sum += counts[idx]; }
    s[t] = sum; __syncthreads();
    for (int off = 128; off > 0; off >>= 1) {
        if (t < off) s[t] += s[t + off];
        __syncthreads();
    }
    if (t == 0) btot[b] = s[0];
}

__global__ __launch_bounds__(256) void scan_btot(const int* __restrict__ btot,
                                                 int* __restrict__ boff,
                                                 int* __restrict__ row_ptr, int nb)
{
    __shared__ int s[256];
    int t = threadIdx.x;
    int v = (t < nb) ? btot[t] : 0;
    s[t] = v; __syncthreads();
    for (int off = 1; off < 256; off <<= 1) {
        int x = (t >= off) ? s[t - off] : 0;
        __syncthreads();
        s[t] += x;
        __syncthreads();
    }
    boff[t] = s[t] - v;                 // exclusive
    if (t == 255) row_ptr[NT] = s[255];
}

__global__ __launch_bounds__(256) void scan_final(const int* __restrict__ counts,
                                                  const int* __restrict__ boff,
                                                  int* __restrict__ row_ptr,
                                                  int* __restrict__ cursor)
{
    __shared__ int s[256];
    int b = blockIdx.x, t = threadIdx.x;
    int base = b * 1024 + t * 4;
    int c[4];
#pragma unroll
    for (int j = 0; j < 4; ++j) { int idx = base + j; c[j] = (idx < NT) ? counts[idx] : 0; }
    int tt = c[0] + c[1] + c[2] + c[3];
    s[t] = tt; __syncthreads();
    for (int off = 1; off < 256; off <<= 1) {
        int x = (t >= off) ? s[t - off] : 0;
        __syncthreads();
        s[t] += x;
        __syncthreads();
    }
    int ex = boff[b] + s[t] - tt;
#pragma unroll
    for (int j = 0; j < 4; ++j) {
        int idx = base + j;
        if (idx < NT) { row_ptr[idx] = ex; cursor[idx] = ex; }
        ex += c[j];
    }
}

// one interleaved 8B write per nnz
__global__ __launch_bounds__(256) void scatter_kernel(
    const int* __restrict__ rows, const int* __restrict__ cols,
    const float* __restrict__ vals, int* __restrict__ cursor,
    int2* __restrict__ csr)
{
    int i = blockIdx.x * 256 + threadIdx.x;
    if (i >= NNZ_TOTAL) return;
    int r = rows[i];
    int pos = atomicAdd(&cursor[r], 1);
    csr[pos] = make_int2(cols[i], __float_as_int(vals[i]));
}

// ---------------- SpMM: R[r] = sum val * E[col] ----------------
// wave per row (lane = dim), full-occupancy grid, 8-wide unroll for 8
// outstanding gathers, scalar row bounds so csr loads can go scalar.
__global__ __launch_bounds__(256) void spmm_kernel(
    const float* __restrict__ E, const int* __restrict__ row_ptr,
    const int2* __restrict__ csr, float* __restrict__ R)
{
    int w = (blockIdx.x * 256 + threadIdx.x) >> 6;   // row
    int lane = threadIdx.x & 63;
    if (w >= NT) return;
    int beg = __builtin_amdgcn_readfirstlane(row_ptr[w]);
    int end = __builtin_amdgcn_readfirstlane(row_ptr[w + 1]);
    float acc = 0.f;
    int j = beg;
    for (; j + 8 <= end; j += 8) {
        int2 p[8];
#pragma unroll
        for (int q = 0; q < 8; ++q) p[q] = csr[j + q];
        float ev[8];
#pragma unroll
        for (int q = 0; q < 8; ++q) ev[q] = E[p[q].x * D + lane];
#pragma unroll
        for (int q = 0; q < 8; ++q) acc += __int_as_float(p[q].y) * ev[q];
    }
    for (; j < end; ++j) {
        int2 p = csr[j];
        acc += __int_as_float(p.y) * E[p.x * D + lane];
    }
    R[w * D + lane] = acc;
}

// ---------------- dense: E <- leakyrelu(R @ W1 + (R .* E) @ W2), in place ----------------
// Persistent waves; both 64x64 weight matrices pinned in VGPRs (column = lane)
// via inline-asm so the compiler cannot re-load them per row.
__global__ __launch_bounds__(256) void dense_kernel(
    const float* __restrict__ R, float* E,
    const float* __restrict__ W1, const float* __restrict__ W2)
{
    __shared__ float2 sAM[4][64];
    int t = threadIdx.x;
    int lane = t & 63;
    int wl = t >> 6;
    float w1r[64], w2r[64];
#pragma unroll
    for (int k = 0; k < 64; ++k) {
        w1r[k] = W1[k * 64 + lane];
        w2r[k] = W2[k * 64 + lane];
    }
#pragma unroll
    for (int k = 0; k < 64; ++k) {
        asm volatile("" : "+v"(w1r[k]), "+v"(w2r[k]));   // pin in VGPRs
    }
    int gw = blockIdx.x * 4 + wl;
    int stride = gridDim.x * 4;
    for (int r = gw; r < NT; r += stride) {
        float a = R[r * D + lane];
        float e = E[r * D + lane];
        sAM[wl][lane] = make_float2(a, a * e);   // wave-private slice; lockstep, no barrier
        float o = 0.f;
#pragma unroll
        for (int k = 0; k < 64; ++k) {
            float2 am = sAM[wl][k];              // uniform-address LDS broadcast
            o += am.x * w1r[k];
            o += am.y * w2r[k];
        }
        o = o > 0.f ? o : ALPHA * o;
        E[r * D + lane] = o;
    }
}

// ---------------- per-stage dot: out[n] += dot(E[n], E[NU+n]) ----------------
__global__ __launch_bounds__(256) void dot_kernel(const float* __restrict__ E,
                                                  float* __restrict__ out)
{
    int w = (blockIdx.x * 256 + threadIdx.x) >> 6;   // user index
    int lane = threadIdx.x & 63;
    if (w >= NU) return;
    float p = E[w * D + lane] * E[(NU + w) * D + lane];
#pragma unroll
    for (int off = 32; off > 0; off >>= 1) p += __shfl_xor(p, off);
    if (lane == 0) out[w] += p;
}

extern "C" void kernel_launch(void* const* d_in, const int* in_sizes, int n_in,
                              void* d_out, int out_size, void* d_ws, size_t ws_size,
                              hipStream_t stream)
{
    const float* ut   = (const float*)d_in[0];
    const float* it   = (const float*)d_in[1];
    const float* W1   = (const float*)d_in[2];
    const float* W2   = (const float*)d_in[3];
    const float* vals = (const float*)d_in[4];
    const int*   rows = (const int*)d_in[5];
    const int*   cols = (const int*)d_in[6];
    const int*   uidx = (const int*)d_in[7];
    const int*   iidx = (const int*)d_in[8];
    float* out = (float*)d_out;

    char* ws = (char*)d_ws;
    float* E       = (float*)(ws + 0);          // 51,200,000 B
    float* R       = (float*)(ws + 51200000);   // 51,200,000 B
    int*   counts  = (int*)  (ws + 102400000);  // 800,000 B
    int*   cursor  = (int*)  (ws + 103200000);  // 800,000 B
    int*   row_ptr = (int*)  (ws + 104000000);  // 800,004 B (padded)
    int*   btot    = (int*)  (ws + 104800256);  // 1 KB
    int*   boff    = (int*)  (ws + 104801280);  // 1 KB
    int2*  csr     = (int2*) (ws + 104802304);  // 25,600,000 B -> end 130,402,304

    hipMemsetAsync(counts, 0, NT * 4, stream);

    init_dot_kernel<<<NU / 4, 256, 0, stream>>>(ut, it, uidx, iidx, E, out);

    hist_kernel<<<(NNZ_TOTAL + 255) / 256, 256, 0, stream>>>(rows, counts);
    const int NB = (NT + 1023) / 1024;          // 196
    scan_block_tot<<<NB, 256, 0, stream>>>(counts, btot);
    scan_btot<<<1, 256, 0, stream>>>(btot, boff, row_ptr, NB);
    scan_final<<<NB, 256, 0, stream>>>(counts, boff, row_ptr, cursor);
    scatter_kernel<<<(NNZ_TOTAL + 255) / 256, 256, 0, stream>>>(rows, cols, vals, cursor, csr);

    for (int l = 0; l < NLAYERS; ++l) {
        spmm_kernel<<<NT / 4, 256, 0, stream>>>(E, row_ptr, csr, R);
        dense_kernel<<<1536, 256, 0, stream>>>(R, E, W1 + l * 4096, W2 + l * 4096);
        dot_kernel<<<NU / 4, 256, 0, stream>>>(E, out);
    }
}

// Round 6
// 903.557 us; speedup vs baseline: 2.1313x; 1.1974x over previous
//
#include <hip/hip_runtime.h>

#define NU 100000
#define NT 200000
#define D 64
#define NLAYERS 3
#define NNZ_TOTAL 3200000
#define ALPHA 0.2f
#define NBUCKET 196      // ceil(NT / 1024)
#define BSHIFT 10        // 1024 rows per bucket
#define CHUNK 4096       // elements per block in binning kernels

// ---------------- fused init + stage-0 dot ----------------
__global__ __launch_bounds__(256) void init_dot_kernel(
    const float* __restrict__ ut, const float* __restrict__ it,
    const int* __restrict__ uidx, const int* __restrict__ iidx,
    float* __restrict__ E, float* __restrict__ out)
{
    int w = (blockIdx.x * 256 + threadIdx.x) >> 6;   // user index
    int lane = threadIdx.x & 63;
    if (w >= NU) return;
    float eu = ut[uidx[w] * D + lane];
    float ei = it[iidx[w] * D + lane];
    E[w * D + lane] = eu;
    E[(NU + w) * D + lane] = ei;
    float p = eu * ei;
#pragma unroll
    for (int off = 32; off > 0; off >>= 1) p += __shfl_xor(p, off);
    if (lane == 0) out[w] = p;
}

// ---------------- CSR build: two-level binning ----------------
// 1) per-bucket histogram (LDS-aggregated)
__global__ __launch_bounds__(256) void bucket_hist_kernel(const int* __restrict__ rows,
                                                          int* __restrict__ bcnt)
{
    __shared__ int l[NBUCKET];
    int t = threadIdx.x;
    for (int k = t; k < NBUCKET; k += 256) l[k] = 0;
    __syncthreads();
    int base = blockIdx.x * CHUNK;
#pragma unroll
    for (int q = 0; q < 16; ++q) {
        int i = base + q * 256 + t;
        if (i < NNZ_TOTAL) atomicAdd(&l[rows[i] >> BSHIFT], 1);
    }
    __syncthreads();
    for (int k = t; k < NBUCKET; k += 256) if (l[k]) atomicAdd(&bcnt[k], l[k]);
}

// 2) exclusive scan of 196 bucket counts (1 block)
__global__ __launch_bounds__(256) void scan_buckets_kernel(const int* __restrict__ bcnt,
                                                           int* __restrict__ bstart,
                                                           int* __restrict__ bcur)
{
    __shared__ int s[256];
    int t = threadIdx.x;
    int v = (t < NBUCKET) ? bcnt[t] : 0;
    s[t] = v; __syncthreads();
    for (int off = 1; off < 256; off <<= 1) {
        int x = (t >= off) ? s[t - off] : 0;
        __syncthreads();
        s[t] += x;
        __syncthreads();
    }
    if (t < NBUCKET) { bstart[t] = s[t] - v; bcur[t] = s[t] - v; }
    if (t == 255) bstart[NBUCKET] = s[255];
}

// 3) bin into bucket-major order; pack (rowlow<<18)|col. Block-aggregated
//    reservations: one global atomic per bucket per block; writes land in
//    ~contiguous per-bucket runs (avg 21 elems = 168B).
__global__ __launch_bounds__(256) void bin_kernel(
    const int* __restrict__ rows, const int* __restrict__ cols,
    const float* __restrict__ vals, int* __restrict__ bcur,
    int2* __restrict__ binned)
{
    __shared__ int lcount[NBUCKET];
    __shared__ int lbase[NBUCKET];
    int t = threadIdx.x;
    for (int k = t; k < NBUCKET; k += 256) lcount[k] = 0;
    __syncthreads();
    int base = blockIdx.x * CHUNK;
    int pk[16];
#pragma unroll
    for (int q = 0; q < 16; ++q) {
        int i = base + q * 256 + t;
        pk[q] = 0;
        if (i < NNZ_TOTAL) {
            int r = rows[i];
            int b = r >> BSHIFT;
            int rank = atomicAdd(&lcount[b], 1);        // rank < 4096 (12 bits)
            pk[q] = (b << 22) | (rank << 10) | (r & 1023);
        }
    }
    __syncthreads();
    for (int k = t; k < NBUCKET; k += 256)
        if (lcount[k]) lbase[k] = atomicAdd(&bcur[k], lcount[k]);
    __syncthreads();
#pragma unroll
    for (int q = 0; q < 16; ++q) {
        int i = base + q * 256 + t;
        if (i < NNZ_TOTAL) {
            int b    = (pk[q] >> 22) & 0xFF;
            int rank = (pk[q] >> 10) & 0xFFF;
            int rl   =  pk[q] & 0x3FF;
            binned[lbase[b] + rank] =
                make_int2((rl << 18) | cols[i], __float_as_int(vals[i]));
        }
    }
}

// 4) per-bucket scatter: builds row_ptr (LDS count + scan of 1024 rows) and
//    the final CSR; all random writes stay inside a 128KB L2-resident window.
__global__ __launch_bounds__(256) void scatter2_kernel(
    const int2* __restrict__ binned, const int* __restrict__ bstart,
    int* __restrict__ row_ptr, int2* __restrict__ csr)
{
    __shared__ int lbuf[1024];
    __shared__ int aux[256];
    int b = blockIdx.x, t = threadIdx.x;
    int rowbase = b << BSHIFT;
    int nrows = min(1024, NT - rowbase);
    int beg = bstart[b], end = bstart[b + 1];
    for (int k = t; k < 1024; k += 256) lbuf[k] = 0;
    __syncthreads();
    for (int i = beg + t; i < end; i += 256)
        atomicAdd(&lbuf[binned[i].x >> 18], 1);
    __syncthreads();
    int c0 = lbuf[t*4], c1 = lbuf[t*4+1], c2 = lbuf[t*4+2], c3 = lbuf[t*4+3];
    int s = c0 + c1 + c2 + c3;
    aux[t] = s; __syncthreads();
    for (int off = 1; off < 256; off <<= 1) {
        int x = (t >= off) ? aux[t - off] : 0;
        __syncthreads();
        aux[t] += x;
        __syncthreads();
    }
    int p0 = beg + aux[t] - s;                 // absolute cursor, exclusive
    int p1 = p0 + c0, p2 = p1 + c1, p3 = p2 + c2;
    lbuf[t*4] = p0; lbuf[t*4+1] = p1; lbuf[t*4+2] = p2; lbuf[t*4+3] = p3;
    if (t*4     < nrows) row_ptr[rowbase + t*4]     = p0;
    if (t*4 + 1 < nrows) row_ptr[rowbase + t*4 + 1] = p1;
    if (t*4 + 2 < nrows) row_ptr[rowbase + t*4 + 2] = p2;
    if (t*4 + 3 < nrows) row_ptr[rowbase + t*4 + 3] = p3;
    if (t == 0) row_ptr[rowbase + nrows] = end;
    __syncthreads();
    for (int i = beg + t; i < end; i += 256) {
        int2 p = binned[i];
        int pos = atomicAdd(&lbuf[p.x >> 18], 1);
        csr[pos] = make_int2(p.x & 0x3FFFF, p.y);
    }
}

// ---------------- SpMM: R[r] = sum val * E[col] ----------------
__global__ __launch_bounds__(256) void spmm_kernel(
    const float* __restrict__ E, const int* __restrict__ row_ptr,
    const int2* __restrict__ csr, float* __restrict__ R)
{
    int w = (blockIdx.x * 256 + threadIdx.x) >> 6;   // row
    int lane = threadIdx.x & 63;
    if (w >= NT) return;
    int beg = __builtin_amdgcn_readfirstlane(row_ptr[w]);
    int end = __builtin_amdgcn_readfirstlane(row_ptr[w + 1]);
    float acc = 0.f;
    int j = beg;
    for (; j + 8 <= end; j += 8) {
        int2 p[8];
#pragma unroll
        for (int q = 0; q < 8; ++q) p[q] = csr[j + q];
        float ev[8];
#pragma unroll
        for (int q = 0; q < 8; ++q) ev[q] = E[p[q].x * D + lane];
#pragma unroll
        for (int q = 0; q < 8; ++q) acc += __int_as_float(p[q].y) * ev[q];
    }
    for (; j < end; ++j) {
        int2 p = csr[j];
        acc += __int_as_float(p.y) * E[p.x * D + lane];
    }
    R[w * D + lane] = acc;
}

// ---------------- dense: E <- leakyrelu(R @ W1 + (R .* E) @ W2), in place ----------------
__global__ __launch_bounds__(256) void dense_kernel(
    const float* __restrict__ R, float* E,
    const float* __restrict__ W1, const float* __restrict__ W2)
{
    __shared__ float2 sAM[4][64];
    int t = threadIdx.x;
    int lane = t & 63;
    int wl = t >> 6;
    float w1r[64], w2r[64];
#pragma unroll
    for (int k = 0; k < 64; ++k) {
        w1r[k] = W1[k * 64 + lane];
        w2r[k] = W2[k * 64 + lane];
    }
#pragma unroll
    for (int k = 0; k < 64; ++k) {
        asm volatile("" : "+v"(w1r[k]), "+v"(w2r[k]));   // pin in VGPRs
    }
    int gw = blockIdx.x * 4 + wl;
    int stride = gridDim.x * 4;
    for (int r = gw; r < NT; r += stride) {
        float a = R[r * D + lane];
        float e = E[r * D + lane];
        sAM[wl][lane] = make_float2(a, a * e);   // wave-private slice; lockstep, no barrier
        float o = 0.f;
#pragma unroll
        for (int k = 0; k < 64; ++k) {
            float2 am = sAM[wl][k];              // uniform-address LDS broadcast
            o += am.x * w1r[k];
            o += am.y * w2r[k];
        }
        o = o > 0.f ? o : ALPHA * o;
        E[r * D + lane] = o;
    }
}

// ---------------- per-stage dot: out[n] += dot(E[n], E[NU+n]) ----------------
__global__ __launch_bounds__(256) void dot_kernel(const float* __restrict__ E,
                                                  float* __restrict__ out)
{
    int w = (blockIdx.x * 256 + threadIdx.x) >> 6;   // user index
    int lane = threadIdx.x & 63;
    if (w >= NU) return;
    float p = E[w * D + lane] * E[(NU + w) * D + lane];
#pragma unroll
    for (int off = 32; off > 0; off >>= 1) p += __shfl_xor(p, off);
    if (lane == 0) out[w] += p;
}

extern "C" void kernel_launch(void* const* d_in, const int* in_sizes, int n_in,
                              void* d_out, int out_size, void* d_ws, size_t ws_size,
                              hipStream_t stream)
{
    const float* ut   = (const float*)d_in[0];
    const float* it   = (const float*)d_in[1];
    const float* W1   = (const float*)d_in[2];
    const float* W2   = (const float*)d_in[3];
    const float* vals = (const float*)d_in[4];
    const int*   rows = (const int*)d_in[5];
    const int*   cols = (const int*)d_in[6];
    const int*   uidx = (const int*)d_in[7];
    const int*   iidx = (const int*)d_in[8];
    float* out = (float*)d_out;

    char* ws = (char*)d_ws;
    float* E       = (float*)(ws + 0);          // 51,200,000 B
    float* R       = (float*)(ws + 51200000);   // 51,200,000 B
    int2*  binned  = (int2*) R;                 // aliases R (used only pre-loop)
    int*   row_ptr = (int*)  (ws + 102400000);  // 800,004 B (pad to 800,256)
    int*   bcnt    = (int*)  (ws + 103200256);  // 784 B (pad 1 KB)
    int*   bstart  = (int*)  (ws + 103201280);  // 788 B (pad 1 KB)
    int*   bcur    = (int*)  (ws + 103202304);  // 784 B (pad 1 KB)
    int2*  csr     = (int2*) (ws + 103203328);  // 25,600,000 B -> end 128,803,328

    hipMemsetAsync(bcnt, 0, NBUCKET * 4, stream);

    init_dot_kernel<<<NU / 4, 256, 0, stream>>>(ut, it, uidx, iidx, E, out);

    const int NBLK = (NNZ_TOTAL + CHUNK - 1) / CHUNK;   // 782
    bucket_hist_kernel<<<NBLK, 256, 0, stream>>>(rows, bcnt);
    scan_buckets_kernel<<<1, 256, 0, stream>>>(bcnt, bstart, bcur);
    bin_kernel<<<NBLK, 256, 0, stream>>>(rows, cols, vals, bcur, binned);
    scatter2_kernel<<<NBUCKET, 256, 0, stream>>>(binned, bstart, row_ptr, csr);

    for (int l = 0; l < NLAYERS; ++l) {
        spmm_kernel<<<NT / 4, 256, 0, stream>>>(E, row_ptr, csr, R);
        dense_kernel<<<1536, 256, 0, stream>>>(R, E, W1 + l * 4096, W2 + l * 4096);
        dot_kernel<<<NU / 4, 256, 0, stream>>>(E, out);
    }
}